// Round 8
// baseline (106.650 us; speedup 1.0000x reference)
//
#include <hip/hip_runtime.h>

typedef float v2f __attribute__((ext_vector_type(2)));

#define D_DIM 512
#define C_CLS 100
#define EPS 1e-8f

// workspace layout (floats)
#define L1_OFF  0
#define DOT_OFF (4096 * 100)
#define XSQ_OFF (2 * 4096 * 100)
#define GSQ_OFF (2 * 4096 * 100 + 4096)

// ---- gsq[c] = sum_d grp[d][c]^2  (grid 25 x 128, 4 classes/block)
__global__ __launch_bounds__(128) void gsq_kernel(const float* __restrict__ grp,
                                                  float* __restrict__ ws) {
    __shared__ float4 red[128];
    const int t = threadIdx.x;
    const int cb = blockIdx.x * 4;
    float4 acc = {0.f, 0.f, 0.f, 0.f};
    for (int d = t; d < D_DIM; d += 128) {
        float4 g = *(const float4*)&grp[d * C_CLS + cb];
        acc.x = fmaf(g.x, g.x, acc.x);
        acc.y = fmaf(g.y, g.y, acc.y);
        acc.z = fmaf(g.z, g.z, acc.z);
        acc.w = fmaf(g.w, g.w, acc.w);
    }
    red[t] = acc;
    __syncthreads();
    for (int off = 64; off > 0; off >>= 1) {
        if (t < off) {
            float4 a = red[t], b = red[t + off];
            a.x += b.x; a.y += b.y; a.z += b.z; a.w += b.w;
            red[t] = a;
        }
        __syncthreads();
    }
    if (t == 0) *(float4*)&ws[GSQ_OFF + cb] = red[0];
}

// ---- l1/dot: one wave = 64 samples (lane = sample) x 4 classes x all 512 d.
// grp address is wave-uniform -> s_load into SGPRs (scalar pipe, no VMEM stall).
// grid = 64 sample-groups * 25 class-quads = 1600 blocks of 64 threads.
__global__ __launch_bounds__(64) void l1dot_kernel(const float* __restrict__ X,
                                                   const float* __restrict__ grp,
                                                   float* __restrict__ ws) {
    const int lane = threadIdx.x;
    const int bid = blockIdx.x;
    const int sg = bid / 25;           // sample group (consecutive bids share X slab)
    const int cg = bid % 25;           // class quad
    const int n = sg * 64 + lane;
    const int cbase = cg * 4;
    const float* xrow = X + (size_t)n * D_DIM;

    float l1a[4] = {0.f, 0.f, 0.f, 0.f};
    v2f dt01 = {0.f, 0.f}, dt23 = {0.f, 0.f};

#pragma unroll 4
    for (int d4 = 0; d4 < D_DIM; d4 += 4) {
        float4 xv = *(const float4*)&xrow[d4];          // per-lane row, L1 line-reused
        float xk[4] = {xv.x, xv.y, xv.z, xv.w};
#pragma unroll
        for (int k = 0; k < 4; ++k) {
            // uniform address -> scalar load (SGPRs)
            float4 g = *(const float4*)&grp[(d4 + k) * C_CLS + cbase];
            v2f g01 = {g.x, g.y};
            v2f g23 = {g.z, g.w};
            v2f x2 = {xk[k], xk[k]};
            v2f e01 = x2 - g01;                          // v_pk_add (neg)
            v2f e23 = x2 - g23;
            l1a[0] += fabsf(e01.x);                      // v_add_f32 abs-mod
            l1a[1] += fabsf(e01.y);
            l1a[2] += fabsf(e23.x);
            l1a[3] += fabsf(e23.y);
            dt01 += x2 * g01;                            // v_pk_fma
            dt23 += x2 * g23;
        }
    }

    *(float4*)&ws[L1_OFF + (size_t)n * C_CLS + cbase] =
        float4{l1a[0], l1a[1], l1a[2], l1a[3]};
    *(float4*)&ws[DOT_OFF + (size_t)n * C_CLS + cbase] =
        float4{dt01.x, dt01.y, dt23.x, dt23.y};

    if (cg == 0) {                                       // uniform branch, 1/25 blocks
        v2f xsq = {0.f, 0.f};
#pragma unroll 4
        for (int d4 = 0; d4 < D_DIM; d4 += 4) {          // rows are L1-hot now
            float4 xv = *(const float4*)&xrow[d4];
            v2f a = {xv.x, xv.y}, b = {xv.z, xv.w};
            xsq += a * a;
            xsq += b * b;
        }
        ws[XSQ_OFF + n] = xsq.x + xsq.y;
    }
}

// ---- finish: softmin(l1) * softmax(cs) * confidence. 8 samples/block.
__global__ __launch_bounds__(256) void fin_kernel(const float* __restrict__ ws,
                                                  float* __restrict__ out) {
    __shared__ float redA[8][25];
    __shared__ float redB[8][25];

    const int t = threadIdx.x;
    const int n0 = blockIdx.x * 8;
    const int s  = t / 25;
    const int c2 = t - s * 25;
    const bool act = (t < 200);
    const int n = n0 + s;

    float l1c[4] = {0.f, 0.f, 0.f, 0.f};
    float dtc[4] = {0.f, 0.f, 0.f, 0.f};
    float cs[4]  = {0.f, 0.f, 0.f, 0.f};

    if (act) {
        float4 a = *(const float4*)&ws[L1_OFF + (size_t)n * C_CLS + c2 * 4];
        float4 b = *(const float4*)&ws[DOT_OFF + (size_t)n * C_CLS + c2 * 4];
        float4 gq = *(const float4*)&ws[GSQ_OFF + c2 * 4];
        float xq = ws[XSQ_OFF + n];
        l1c[0] = a.x; l1c[1] = a.y; l1c[2] = a.z; l1c[3] = a.w;
        dtc[0] = b.x; dtc[1] = b.y; dtc[2] = b.z; dtc[3] = b.w;
        float gs[4] = {gq.x, gq.y, gq.z, gq.w};
#pragma unroll
        for (int c = 0; c < 4; ++c)
            cs[c] = dtc[c] / fmaxf(sqrtf(xq * gs[c]), EPS);
        redA[s][c2] = fminf(fminf(l1c[0], l1c[1]), fminf(l1c[2], l1c[3]));
        redB[s][c2] = fmaxf(fmaxf(cs[0], cs[1]), fmaxf(cs[2], cs[3]));
    }
    __syncthreads();

    float minl1 = 0.f, maxcs = 0.f;
    if (act) {
        minl1 = redA[s][0];
        maxcs = redB[s][0];
        for (int k = 1; k < 25; ++k) {
            minl1 = fminf(minl1, redA[s][k]);
            maxcs = fmaxf(maxcs, redB[s][k]);
        }
    }
    __syncthreads();

    if (act) {
        redA[s][c2] = __expf(minl1 - l1c[0]) + __expf(minl1 - l1c[1]) +
                      __expf(minl1 - l1c[2]) + __expf(minl1 - l1c[3]);
        redB[s][c2] = __expf(cs[0] - maxcs) + __expf(cs[1] - maxcs) +
                      __expf(cs[2] - maxcs) + __expf(cs[3] - maxcs);
    }
    __syncthreads();

    if (act) {
        float s1 = 0.f, s2 = 0.f;
        for (int k = 0; k < 25; ++k) { s1 += redA[s][k]; s2 += redB[s][k]; }
        float f = maxcs / (s1 * s2);
        float4 o;
        o.x = f * __expf(cs[0] - maxcs) * __expf(minl1 - l1c[0]);
        o.y = f * __expf(cs[1] - maxcs) * __expf(minl1 - l1c[1]);
        o.z = f * __expf(cs[2] - maxcs) * __expf(minl1 - l1c[2]);
        o.w = f * __expf(cs[3] - maxcs) * __expf(minl1 - l1c[3]);
        *(float4*)&out[(size_t)n * C_CLS + c2 * 4] = o;
    }
}

extern "C" void kernel_launch(void* const* d_in, const int* in_sizes, int n_in,
                              void* d_out, int out_size, void* d_ws, size_t ws_size,
                              hipStream_t stream) {
    const float* X   = (const float*)d_in[0];   // [4096, 512] f32
    const float* grp = (const float*)d_in[1];   // [1, 512, 100] f32
    float* out = (float*)d_out;                 // [4096, 100] f32
    float* ws  = (float*)d_ws;                  // ~3.3 MB f32 scratch

    gsq_kernel<<<25, 128, 0, stream>>>(grp, ws);
    l1dot_kernel<<<64 * 25, 64, 0, stream>>>(X, grp, ws);
    fin_kernel<<<4096 / 8, 256, 0, stream>>>(ws, out);
}

// Round 9
// 35.770 us; speedup vs baseline: 2.9816x; 2.9816x over previous
//
#include <hip/hip_runtime.h>

typedef float v2f __attribute__((ext_vector_type(2)));

#define D_DIM 512
#define C_CLS 100
#define SAMP 4     // samples per block
#define NT 256     // threads; 200 active = 8 dq * 25 cq

// No X staging: X slab is 8 KB/block, read via same-address L1 broadcasts.
// d-slices interleaved (d = j*32 + dq*4) so the block's live grp window is
// 32 rows = 12.8 KB -> L1-resident alongside X.
__global__ __launch_bounds__(NT, 6) void cls_kernel(const float* __restrict__ X,
                                                    const float* __restrict__ grp,
                                                    float* __restrict__ out) {
    __shared__ float4 pA[SAMP][8][25];   // l1  partials [si][dq][cq]
    __shared__ float4 pB[SAMP][8][25];   // dot partials
    __shared__ float4 pG[8][25];         // gsq partials [dq][cq]
    __shared__ float redA[SAMP][25];
    __shared__ float redB[SAMP][25];
    __shared__ float xsqs[SAMP];

    const int t = threadIdx.x;
    const int n0 = blockIdx.x * SAMP;
    const float* xb = X + (size_t)n0 * D_DIM;

    // ||x||^2 per sample row: 32 threads/row, global reads (L1-warming), shuffle-reduce
    if (t < 128) {
        const int r = t >> 5, j = t & 31;
        float v = 0.f;
#pragma unroll
        for (int k = 0; k < 4; ++k) {
            float4 a = *(const float4*)&xb[(size_t)r * D_DIM + j * 4 + k * 128];
            v += a.x * a.x + a.y * a.y + a.z * a.z + a.w * a.w;
        }
#pragma unroll
        for (int m = 16; m > 0; m >>= 1) v += __shfl_xor(v, m, 32);
        if (j == 0) xsqs[r] = v;
    }

    const bool act = (t < 200);
    const int dq = t / 25;
    const int cq = t - dq * 25;

    float l1[4][4];
    v2f dtl[4], dth[4];
    v2f gsql = {0.f, 0.f}, gsqh = {0.f, 0.f};
#pragma unroll
    for (int i = 0; i < 4; ++i) {
        dtl[i] = (v2f){0.f, 0.f};
        dth[i] = (v2f){0.f, 0.f};
#pragma unroll
        for (int j = 0; j < 4; ++j) l1[i][j] = 0.f;
    }

    if (act) {
        const float* gp = grp + cq * 4;
#pragma unroll 2
        for (int j = 0; j < 16; ++j) {
            const int d4 = j * 32 + dq * 4;      // interleaved d-slice
            float xr[4][4];   // [si][k]
#pragma unroll
            for (int si = 0; si < 4; ++si)
                *(float4*)&xr[si][0] = *(const float4*)&xb[si * D_DIM + d4];
#pragma unroll
            for (int k = 0; k < 4; ++k) {
                float4 g4 = *(const float4*)&gp[(d4 + k) * C_CLS];
                v2f glo = {g4.x, g4.y};
                v2f ghi = {g4.z, g4.w};
                gsql += glo * glo;
                gsqh += ghi * ghi;
#pragma unroll
                for (int si = 0; si < 4; ++si) {
                    float x = xr[si][k];
                    v2f x2 = {x, x};
                    v2f el = x2 - glo;
                    v2f eh = x2 - ghi;
                    l1[si][0] += fabsf(el.x);
                    l1[si][1] += fabsf(el.y);
                    l1[si][2] += fabsf(eh.x);
                    l1[si][3] += fabsf(eh.y);
                    dtl[si] += x2 * glo;
                    dth[si] += x2 * ghi;
                }
            }
        }
#pragma unroll
        for (int si = 0; si < 4; ++si) {
            pA[si][dq][cq] = float4{l1[si][0], l1[si][1], l1[si][2], l1[si][3]};
            pB[si][dq][cq] = float4{dtl[si].x, dtl[si].y, dth[si].x, dth[si].y};
        }
        pG[dq][cq] = float4{gsql.x, gsql.y, gsqh.x, gsqh.y};
    }
    __syncthreads();

    // Phase 2: thread (s = t/25 in 0..3, c2 = t%25) combines 8 dq partials
    const int s  = t / 25;
    const int c2 = t - s * 25;
    const bool act2 = (t < 100);

    float l1c[4] = {0.f, 0.f, 0.f, 0.f};
    float dtc[4] = {0.f, 0.f, 0.f, 0.f};
    float gsc[4] = {0.f, 0.f, 0.f, 0.f};
    if (act2) {
#pragma unroll
        for (int q = 0; q < 8; ++q) {
            float4 a = pA[s][q][c2];
            float4 b = pB[s][q][c2];
            float4 c = pG[q][c2];
            l1c[0] += a.x; l1c[1] += a.y; l1c[2] += a.z; l1c[3] += a.w;
            dtc[0] += b.x; dtc[1] += b.y; dtc[2] += b.z; dtc[3] += b.w;
            gsc[0] += c.x; gsc[1] += c.y; gsc[2] += c.z; gsc[3] += c.w;
        }
    }

    float cs[4] = {0.f, 0.f, 0.f, 0.f};
    if (act2) {
        float xq = xsqs[s];
#pragma unroll
        for (int c = 0; c < 4; ++c)
            cs[c] = dtc[c] / fmaxf(sqrtf(xq * gsc[c]), 1e-8f);
        redA[s][c2] = fminf(fminf(l1c[0], l1c[1]), fminf(l1c[2], l1c[3]));
        redB[s][c2] = fmaxf(fmaxf(cs[0], cs[1]), fmaxf(cs[2], cs[3]));
    }
    __syncthreads();

    float minl1 = 0.f, maxcs = 0.f;
    if (act2) {
        minl1 = redA[s][0];
        maxcs = redB[s][0];
        for (int k = 1; k < 25; ++k) {
            minl1 = fminf(minl1, redA[s][k]);
            maxcs = fmaxf(maxcs, redB[s][k]);
        }
    }
    __syncthreads();

    if (act2) {
        redA[s][c2] = __expf(minl1 - l1c[0]) + __expf(minl1 - l1c[1]) +
                      __expf(minl1 - l1c[2]) + __expf(minl1 - l1c[3]);
        redB[s][c2] = __expf(cs[0] - maxcs) + __expf(cs[1] - maxcs) +
                      __expf(cs[2] - maxcs) + __expf(cs[3] - maxcs);
    }
    __syncthreads();

    if (act2) {
        float s1 = 0.f, s2 = 0.f;
        for (int k = 0; k < 25; ++k) { s1 += redA[s][k]; s2 += redB[s][k]; }
        float f = maxcs / (s1 * s2);
        float4 o;
        o.x = f * __expf(cs[0] - maxcs) * __expf(minl1 - l1c[0]);
        o.y = f * __expf(cs[1] - maxcs) * __expf(minl1 - l1c[1]);
        o.z = f * __expf(cs[2] - maxcs) * __expf(minl1 - l1c[2]);
        o.w = f * __expf(cs[3] - maxcs) * __expf(minl1 - l1c[3]);
        *(float4*)&out[(size_t)(n0 + s) * C_CLS + c2 * 4] = o;
    }
}

extern "C" void kernel_launch(void* const* d_in, const int* in_sizes, int n_in,
                              void* d_out, int out_size, void* d_ws, size_t ws_size,
                              hipStream_t stream) {
    const float* X   = (const float*)d_in[0];   // [4096, 512] f32
    const float* grp = (const float*)d_in[1];   // [1, 512, 100] f32
    float* out = (float*)d_out;                 // [4096, 100] f32
    (void)d_ws; (void)ws_size;

    cls_kernel<<<4096 / SAMP, NT, 0, stream>>>(X, grp, out);
}

// Round 10
// 35.734 us; speedup vs baseline: 2.9846x; 1.0010x over previous
//
#include <hip/hip_runtime.h>

typedef float v2f __attribute__((ext_vector_type(2)));

#define D_DIM 512
#define C_CLS 100
#define SAMP 2     // samples per block -> grid 2048 = 8 blocks/CU (occupancy!)
#define NT 256     // threads; 200 active = 8 dq * 25 cq

// No X staging (X slab 4 KB/block, same-address L1 broadcasts across cq lanes).
// d-slices interleaved (d = j*32 + dq*4): block's live grp window = 12.8 KB.
__global__ __launch_bounds__(NT, 6) void cls_kernel(const float* __restrict__ X,
                                                    const float* __restrict__ grp,
                                                    float* __restrict__ out) {
    __shared__ float4 pA[SAMP][8][25];   // l1  partials [si][dq][cq]
    __shared__ float4 pB[SAMP][8][25];   // dot partials
    __shared__ float4 pG[8][25];         // gsq partials [dq][cq]
    __shared__ float redA[SAMP][25];
    __shared__ float redB[SAMP][25];
    __shared__ float xsqs[SAMP];

    const int t = threadIdx.x;
    const int n0 = blockIdx.x * SAMP;
    const float* xb = X + (size_t)n0 * D_DIM;

    // ||x||^2 per sample row: 32 threads/row, shuffle-reduce (also warms L1)
    if (t < 32 * SAMP) {
        const int r = t >> 5, j = t & 31;
        float v = 0.f;
#pragma unroll
        for (int k = 0; k < 4; ++k) {
            float4 a = *(const float4*)&xb[(size_t)r * D_DIM + j * 4 + k * 128];
            v += a.x * a.x + a.y * a.y + a.z * a.z + a.w * a.w;
        }
#pragma unroll
        for (int m = 16; m > 0; m >>= 1) v += __shfl_xor(v, m, 32);
        if (j == 0) xsqs[r] = v;
    }

    const bool act = (t < 200);
    const int dq = t / 25;
    const int cq = t - dq * 25;

    float l1[SAMP][4];
    v2f dtl[SAMP], dth[SAMP];
    v2f gsql = {0.f, 0.f}, gsqh = {0.f, 0.f};
#pragma unroll
    for (int i = 0; i < SAMP; ++i) {
        dtl[i] = (v2f){0.f, 0.f};
        dth[i] = (v2f){0.f, 0.f};
#pragma unroll
        for (int j = 0; j < 4; ++j) l1[i][j] = 0.f;
    }

    if (act) {
        const float* gp = grp + cq * 4;
#pragma unroll 2
        for (int j = 0; j < 16; ++j) {
            const int d4 = j * 32 + dq * 4;      // interleaved d-slice
            float xr[SAMP][4];
#pragma unroll
            for (int si = 0; si < SAMP; ++si)
                *(float4*)&xr[si][0] = *(const float4*)&xb[si * D_DIM + d4];
#pragma unroll
            for (int k = 0; k < 4; ++k) {
                float4 g4 = *(const float4*)&gp[(d4 + k) * C_CLS];
                v2f glo = {g4.x, g4.y};
                v2f ghi = {g4.z, g4.w};
                gsql += glo * glo;
                gsqh += ghi * ghi;
#pragma unroll
                for (int si = 0; si < SAMP; ++si) {
                    float x = xr[si][k];
                    v2f x2 = {x, x};
                    v2f el = x2 - glo;
                    v2f eh = x2 - ghi;
                    l1[si][0] += fabsf(el.x);
                    l1[si][1] += fabsf(el.y);
                    l1[si][2] += fabsf(eh.x);
                    l1[si][3] += fabsf(eh.y);
                    dtl[si] += x2 * glo;
                    dth[si] += x2 * ghi;
                }
            }
        }
#pragma unroll
        for (int si = 0; si < SAMP; ++si) {
            pA[si][dq][cq] = float4{l1[si][0], l1[si][1], l1[si][2], l1[si][3]};
            pB[si][dq][cq] = float4{dtl[si].x, dtl[si].y, dth[si].x, dth[si].y};
        }
        pG[dq][cq] = float4{gsql.x, gsql.y, gsqh.x, gsqh.y};
    }
    __syncthreads();

    // Phase 2: thread (s = t/25 in 0..1, c2 = t%25) combines 8 dq partials
    const int s  = t / 25;
    const int c2 = t - s * 25;
    const bool act2 = (t < 25 * SAMP);

    float l1c[4] = {0.f, 0.f, 0.f, 0.f};
    float dtc[4] = {0.f, 0.f, 0.f, 0.f};
    float gsc[4] = {0.f, 0.f, 0.f, 0.f};
    if (act2) {
#pragma unroll
        for (int q = 0; q < 8; ++q) {
            float4 a = pA[s][q][c2];
            float4 b = pB[s][q][c2];
            float4 c = pG[q][c2];
            l1c[0] += a.x; l1c[1] += a.y; l1c[2] += a.z; l1c[3] += a.w;
            dtc[0] += b.x; dtc[1] += b.y; dtc[2] += b.z; dtc[3] += b.w;
            gsc[0] += c.x; gsc[1] += c.y; gsc[2] += c.z; gsc[3] += c.w;
        }
    }

    float cs[4] = {0.f, 0.f, 0.f, 0.f};
    if (act2) {
        float xq = xsqs[s];
#pragma unroll
        for (int c = 0; c < 4; ++c)
            cs[c] = dtc[c] / fmaxf(sqrtf(xq * gsc[c]), 1e-8f);
        redA[s][c2] = fminf(fminf(l1c[0], l1c[1]), fminf(l1c[2], l1c[3]));
        redB[s][c2] = fmaxf(fmaxf(cs[0], cs[1]), fmaxf(cs[2], cs[3]));
    }
    __syncthreads();

    float minl1 = 0.f, maxcs = 0.f;
    if (act2) {
        minl1 = redA[s][0];
        maxcs = redB[s][0];
        for (int k = 1; k < 25; ++k) {
            minl1 = fminf(minl1, redA[s][k]);
            maxcs = fmaxf(maxcs, redB[s][k]);
        }
    }
    __syncthreads();

    if (act2) {
        redA[s][c2] = __expf(minl1 - l1c[0]) + __expf(minl1 - l1c[1]) +
                      __expf(minl1 - l1c[2]) + __expf(minl1 - l1c[3]);
        redB[s][c2] = __expf(cs[0] - maxcs) + __expf(cs[1] - maxcs) +
                      __expf(cs[2] - maxcs) + __expf(cs[3] - maxcs);
    }
    __syncthreads();

    if (act2) {
        float s1 = 0.f, s2 = 0.f;
        for (int k = 0; k < 25; ++k) { s1 += redA[s][k]; s2 += redB[s][k]; }
        float f = maxcs / (s1 * s2);
        float4 o;
        o.x = f * __expf(cs[0] - maxcs) * __expf(minl1 - l1c[0]);
        o.y = f * __expf(cs[1] - maxcs) * __expf(minl1 - l1c[1]);
        o.z = f * __expf(cs[2] - maxcs) * __expf(minl1 - l1c[2]);
        o.w = f * __expf(cs[3] - maxcs) * __expf(minl1 - l1c[3]);
        *(float4*)&out[(size_t)(n0 + s) * C_CLS + c2 * 4] = o;
    }
}

extern "C" void kernel_launch(void* const* d_in, const int* in_sizes, int n_in,
                              void* d_out, int out_size, void* d_ws, size_t ws_size,
                              hipStream_t stream) {
    const float* X   = (const float*)d_in[0];   // [4096, 512] f32
    const float* grp = (const float*)d_in[1];   // [1, 512, 100] f32
    float* out = (float*)d_out;                 // [4096, 100] f32
    (void)d_ws; (void)ws_size;

    cls_kernel<<<4096 / SAMP, NT, 0, stream>>>(X, grp, out);
}

// Round 11
// 34.562 us; speedup vs baseline: 3.0857x; 1.0339x over previous
//
#include <hip/hip_runtime.h>

typedef float v2f __attribute__((ext_vector_type(2)));

#define D_DIM 512
#define C_CLS 100
#define SAMP 2     // samples per block -> grid 2048 = 8 blocks/CU
#define NT 256     // threads; 200 active = 8 dq * 25 cq

// ---- forced VOP3P codegen ----
// packed subtract: d = {splat - b.lo, splat - b.hi}, splat = src0.lo (L) or src0.hi (H)
#define PKSUBL(d, xp, g) asm("v_pk_add_f32 %0, %1, %2 op_sel:[0,0] op_sel_hi:[0,1] neg_lo:[0,1] neg_hi:[0,1]" : "=v"(d) : "v"(xp), "v"(g))
#define PKSUBH(d, xp, g) asm("v_pk_add_f32 %0, %1, %2 op_sel:[1,0] op_sel_hi:[1,1] neg_lo:[0,1] neg_hi:[0,1]" : "=v"(d) : "v"(xp), "v"(g))
// packed fma with splat src0: acc += splat * b
#define PKFMAL(acc, xp, g) asm("v_pk_fma_f32 %0, %1, %2, %0 op_sel:[0,0,0] op_sel_hi:[0,1,1]" : "+v"(acc) : "v"(xp), "v"(g))
#define PKFMAH(acc, xp, g) asm("v_pk_fma_f32 %0, %1, %2, %0 op_sel:[1,0,0] op_sel_hi:[1,1,1]" : "+v"(acc) : "v"(xp), "v"(g))
// plain packed fma: acc += a*b
#define PKFMA(acc, a, b)   asm("v_pk_fma_f32 %0, %1, %2, %0" : "+v"(acc) : "v"(a), "v"(b))
// forced abs-fold accumulate: acc += |v|  (single VOP3 with input modifier)
#define ABSADD(acc, v)     asm("v_add_f32 %0, |%1|, %0" : "+v"(acc) : "v"(v))

// one (k, si) step: 2 pk_sub + 4 abs-add + 2 pk_fma for 4 classes
#define KSTEP(SUB, FMA, xp, si)                                   \
    { v2f el_, eh_;                                               \
      SUB(el_, xp, glo); SUB(eh_, xp, ghi);                       \
      ABSADD(l1[si][0], el_.x); ABSADD(l1[si][1], el_.y);         \
      ABSADD(l1[si][2], eh_.x); ABSADD(l1[si][3], eh_.y);         \
      FMA(dtl[si], xp, glo); FMA(dth[si], xp, ghi); }

__global__ __launch_bounds__(NT, 6) void cls_kernel(const float* __restrict__ X,
                                                    const float* __restrict__ grp,
                                                    float* __restrict__ out) {
    __shared__ float4 pA[SAMP][8][25];   // l1  partials [si][dq][cq]
    __shared__ float4 pB[SAMP][8][25];   // dot partials
    __shared__ float4 pG[8][25];         // gsq partials [dq][cq]
    __shared__ float redA[SAMP][25];
    __shared__ float redB[SAMP][25];
    __shared__ float xsqs[SAMP];

    const int t = threadIdx.x;
    const int n0 = blockIdx.x * SAMP;
    const float* xb = X + (size_t)n0 * D_DIM;

    // ||x||^2 per sample row: 32 threads/row, shuffle-reduce
    if (t < 32 * SAMP) {
        const int r = t >> 5, j = t & 31;
        float v = 0.f;
#pragma unroll
        for (int k = 0; k < 4; ++k) {
            float4 a = *(const float4*)&xb[(size_t)r * D_DIM + j * 4 + k * 128];
            v += a.x * a.x + a.y * a.y + a.z * a.z + a.w * a.w;
        }
#pragma unroll
        for (int m = 16; m > 0; m >>= 1) v += __shfl_xor(v, m, 32);
        if (j == 0) xsqs[r] = v;
    }

    const bool act = (t < 200);
    const int dq = t / 25;
    const int cq = t - dq * 25;

    float l1[SAMP][4];
    v2f dtl[SAMP], dth[SAMP];
    v2f gsql = {0.f, 0.f}, gsqh = {0.f, 0.f};
#pragma unroll
    for (int i = 0; i < SAMP; ++i) {
        dtl[i] = (v2f){0.f, 0.f};
        dth[i] = (v2f){0.f, 0.f};
#pragma unroll
        for (int j = 0; j < 4; ++j) l1[i][j] = 0.f;
    }

    if (act) {
        const float4* gp = (const float4*)(grp + cq * 4);   // row stride 25 float4
#pragma unroll 2
        for (int j = 0; j < 16; ++j) {
            const int d4 = j * 32 + dq * 4;      // interleaved d-slice
            float4 xv0 = *(const float4*)&xb[0 * D_DIM + d4];
            float4 xv1 = *(const float4*)&xb[1 * D_DIM + d4];
            v2f x0l = {xv0.x, xv0.y}, x0h = {xv0.z, xv0.w};
            v2f x1l = {xv1.x, xv1.y}, x1h = {xv1.z, xv1.w};

            {   // k = 0 (x = pair.lo of xl)
                float4 g4 = gp[(d4 + 0) * 25];
                v2f glo = {g4.x, g4.y}, ghi = {g4.z, g4.w};
                PKFMA(gsql, glo, glo); PKFMA(gsqh, ghi, ghi);
                KSTEP(PKSUBL, PKFMAL, x0l, 0)
                KSTEP(PKSUBL, PKFMAL, x1l, 1)
            }
            {   // k = 1 (x = pair.hi of xl)
                float4 g4 = gp[(d4 + 1) * 25];
                v2f glo = {g4.x, g4.y}, ghi = {g4.z, g4.w};
                PKFMA(gsql, glo, glo); PKFMA(gsqh, ghi, ghi);
                KSTEP(PKSUBH, PKFMAH, x0l, 0)
                KSTEP(PKSUBH, PKFMAH, x1l, 1)
            }
            {   // k = 2 (x = pair.lo of xh)
                float4 g4 = gp[(d4 + 2) * 25];
                v2f glo = {g4.x, g4.y}, ghi = {g4.z, g4.w};
                PKFMA(gsql, glo, glo); PKFMA(gsqh, ghi, ghi);
                KSTEP(PKSUBL, PKFMAL, x0h, 0)
                KSTEP(PKSUBL, PKFMAL, x1h, 1)
            }
            {   // k = 3 (x = pair.hi of xh)
                float4 g4 = gp[(d4 + 3) * 25];
                v2f glo = {g4.x, g4.y}, ghi = {g4.z, g4.w};
                PKFMA(gsql, glo, glo); PKFMA(gsqh, ghi, ghi);
                KSTEP(PKSUBH, PKFMAH, x0h, 0)
                KSTEP(PKSUBH, PKFMAH, x1h, 1)
            }
        }
#pragma unroll
        for (int si = 0; si < SAMP; ++si) {
            pA[si][dq][cq] = float4{l1[si][0], l1[si][1], l1[si][2], l1[si][3]};
            pB[si][dq][cq] = float4{dtl[si].x, dtl[si].y, dth[si].x, dth[si].y};
        }
        pG[dq][cq] = float4{gsql.x, gsql.y, gsqh.x, gsqh.y};
    }
    __syncthreads();

    // Phase 2: thread (s = t/25, c2 = t%25) combines 8 dq partials
    const int s  = t / 25;
    const int c2 = t - s * 25;
    const bool act2 = (t < 25 * SAMP);

    float l1c[4] = {0.f, 0.f, 0.f, 0.f};
    float dtc[4] = {0.f, 0.f, 0.f, 0.f};
    float gsc[4] = {0.f, 0.f, 0.f, 0.f};
    if (act2) {
#pragma unroll
        for (int q = 0; q < 8; ++q) {
            float4 a = pA[s][q][c2];
            float4 b = pB[s][q][c2];
            float4 c = pG[q][c2];
            l1c[0] += a.x; l1c[1] += a.y; l1c[2] += a.z; l1c[3] += a.w;
            dtc[0] += b.x; dtc[1] += b.y; dtc[2] += b.z; dtc[3] += b.w;
            gsc[0] += c.x; gsc[1] += c.y; gsc[2] += c.z; gsc[3] += c.w;
        }
    }

    float cs[4] = {0.f, 0.f, 0.f, 0.f};
    if (act2) {
        float xq = xsqs[s];
#pragma unroll
        for (int c = 0; c < 4; ++c)
            cs[c] = dtc[c] / fmaxf(sqrtf(xq * gsc[c]), 1e-8f);
        redA[s][c2] = fminf(fminf(l1c[0], l1c[1]), fminf(l1c[2], l1c[3]));
        redB[s][c2] = fmaxf(fmaxf(cs[0], cs[1]), fmaxf(cs[2], cs[3]));
    }
    __syncthreads();

    float minl1 = 0.f, maxcs = 0.f;
    if (act2) {
        minl1 = redA[s][0];
        maxcs = redB[s][0];
        for (int k = 1; k < 25; ++k) {
            minl1 = fminf(minl1, redA[s][k]);
            maxcs = fmaxf(maxcs, redB[s][k]);
        }
    }
    __syncthreads();

    if (act2) {
        redA[s][c2] = __expf(minl1 - l1c[0]) + __expf(minl1 - l1c[1]) +
                      __expf(minl1 - l1c[2]) + __expf(minl1 - l1c[3]);
        redB[s][c2] = __expf(cs[0] - maxcs) + __expf(cs[1] - maxcs) +
                      __expf(cs[2] - maxcs) + __expf(cs[3] - maxcs);
    }
    __syncthreads();

    if (act2) {
        float s1 = 0.f, s2 = 0.f;
        for (int k = 0; k < 25; ++k) { s1 += redA[s][k]; s2 += redB[s][k]; }
        float f = maxcs / (s1 * s2);
        float4 o;
        o.x = f * __expf(cs[0] - maxcs) * __expf(minl1 - l1c[0]);
        o.y = f * __expf(cs[1] - maxcs) * __expf(minl1 - l1c[1]);
        o.z = f * __expf(cs[2] - maxcs) * __expf(minl1 - l1c[2]);
        o.w = f * __expf(cs[3] - maxcs) * __expf(minl1 - l1c[3]);
        *(float4*)&out[(size_t)(n0 + s) * C_CLS + c2 * 4] = o;
    }
}

extern "C" void kernel_launch(void* const* d_in, const int* in_sizes, int n_in,
                              void* d_out, int out_size, void* d_ws, size_t ws_size,
                              hipStream_t stream) {
    const float* X   = (const float*)d_in[0];   // [4096, 512] f32
    const float* grp = (const float*)d_in[1];   // [1, 512, 100] f32
    float* out = (float*)d_out;                 // [4096, 100] f32
    (void)d_ws; (void)ws_size;

    cls_kernel<<<4096 / SAMP, NT, 0, stream>>>(X, grp, out);
}